// Round 1
// baseline (697.065 us; speedup 1.0000x reference)
//
#include <hip/hip_runtime.h>
#include <hip/hip_bf16.h>
#include <stdint.h>

// EfficientAttention: B=16, C=512, HW=4096, HEADS=8, hk=hv=64
// N = B*HW = 65536.  All big matmuls in bf16 MFMA (16x16x32), fp32 accum.

typedef __attribute__((ext_vector_type(8))) short bf16x8;
typedef __attribute__((ext_vector_type(8))) unsigned short u16x8;
typedef __attribute__((ext_vector_type(4))) unsigned short u16x4;
typedef __attribute__((ext_vector_type(4))) float f32x4;

__device__ __forceinline__ float bf2f(unsigned short u) {
  union { unsigned int i; float f; } v; v.i = ((unsigned int)u) << 16; return v.f;
}
__device__ __forceinline__ unsigned short f2bf(float f) {
  union { float f; unsigned int i; } v; v.f = f;
  unsigned int u = v.i;
  return (unsigned short)((u + 0x7FFFu + ((u >> 16) & 1u)) >> 16);
}
__device__ __forceinline__ void gl_lds16(const void* g, void* l) {
  __builtin_amdgcn_global_load_lds((const __attribute__((address_space(1))) void*)g,
                                   (__attribute__((address_space(3))) void*)l, 16, 0, 0);
}

// ---------------- K0: pack Wk|Wq|Wv (stacked) to bf16 -----------------------
__global__ void k0_pack_w(const float* __restrict__ Wk, const float* __restrict__ Wq,
                          const float* __restrict__ Wv, unsigned short* __restrict__ Wkqv) {
  int idx = blockIdx.x * 256 + threadIdx.x;   // < 1536*512
  int o = idx >> 9, c = idx & 511;
  float v;
  if (o < 512) v = Wk[o * 512 + c];
  else if (o < 1024) v = Wq[(o - 512) * 512 + c];
  else v = Wv[(o - 1024) * 512 + c];
  Wkqv[idx] = f2bf(v);
}

// ---------------- K1: x[b][c][l] fp32 -> XbT[b*4096+l][c] bf16 (transpose) --
__global__ void k1_transpose_x(const float* __restrict__ x, unsigned short* __restrict__ XbT) {
  __shared__ unsigned short ts[64][68];      // pad to break bank conflicts
  int l0 = blockIdx.x * 64, c0 = blockIdx.y * 64, b = blockIdx.z;
  int t = threadIdx.x;
  const float* xb = x + (size_t)b * (512 * 4096);
#pragma unroll
  for (int i = 0; i < 4; i++) {
    int f = i * 256 + t;
    int cl = f >> 4, l4 = (f & 15) * 4;
    const float4 v = *(const float4*)(xb + (size_t)(c0 + cl) * 4096 + l0 + l4);
    ts[cl][l4]     = f2bf(v.x);
    ts[cl][l4 + 1] = f2bf(v.y);
    ts[cl][l4 + 2] = f2bf(v.z);
    ts[cl][l4 + 3] = f2bf(v.w);
  }
  __syncthreads();
#pragma unroll
  for (int i = 0; i < 4; i++) {
    int wv = i * 256 + t;
    int ll = wv >> 4, c4 = (wv & 15) * 4;
    u16x4 o;
    o.x = ts[c4][ll]; o.y = ts[c4 + 1][ll]; o.z = ts[c4 + 2][ll]; o.w = ts[c4 + 3][ll];
    *(u16x4*)(XbT + (size_t)(b * 4096 + l0 + ll) * 512 + c0 + c4) = o;
  }
}

// ---------------- K2: KQV[o][n] = Wkqv[o][:] . XbT[n][:] + bias, bf16 out ---
// m97-style: 128x128 tile, BK=32, global_load_lds(16B), 4 waves of 64x64.
__global__ void __launch_bounds__(256) k2_gemm_kqv(
    const unsigned short* __restrict__ Wkqv, const unsigned short* __restrict__ XbT,
    const float* __restrict__ bk, const float* __restrict__ bq, const float* __restrict__ bvv,
    unsigned short* __restrict__ KQV) {
  __shared__ unsigned short As[128 * 32];
  __shared__ unsigned short Bs[128 * 32];
  const int t = threadIdx.x;
  const int lane = t & 63, w = t >> 6;
  const int wm = w >> 1, wn = w & 1;
  const int m0 = blockIdx.x * 128, n0 = blockIdx.y * 128;
  const int col = lane & 15, quad = lane >> 4;

  f32x4 zero = {0.f, 0.f, 0.f, 0.f};
  f32x4 acc[4][4];
#pragma unroll
  for (int i = 0; i < 4; i++)
#pragma unroll
    for (int j = 0; j < 4; j++) acc[i][j] = zero;

  for (int kt = 0; kt < 16; kt++) {
    const int k0 = kt * 32;
    __syncthreads();
#pragma unroll
    for (int i = 0; i < 2; i++) {
      int lin = i * 256 + t;
      int row = lin >> 2, seg = lin & 3;
      gl_lds16(Wkqv + (size_t)(m0 + row) * 512 + k0 + seg * 8,
               (char*)As + (i * 256 + (t & ~63)) * 16);
      gl_lds16(XbT + (size_t)(n0 + row) * 512 + k0 + seg * 8,
               (char*)Bs + (i * 256 + (t & ~63)) * 16);
    }
    __syncthreads();
    bf16x8 a[4], bf[4];
#pragma unroll
    for (int mt = 0; mt < 4; mt++)
      a[mt] = *(const bf16x8*)(As + (wm * 64 + mt * 16 + col) * 32 + quad * 8);
#pragma unroll
    for (int nt = 0; nt < 4; nt++)
      bf[nt] = *(const bf16x8*)(Bs + (wn * 64 + nt * 16 + col) * 32 + quad * 8);
#pragma unroll
    for (int mt = 0; mt < 4; mt++)
#pragma unroll
      for (int nt = 0; nt < 4; nt++)
        acc[mt][nt] = __builtin_amdgcn_mfma_f32_16x16x32_bf16(a[mt], bf[nt], acc[mt][nt], 0, 0, 0);
  }
#pragma unroll
  for (int mt = 0; mt < 4; mt++) {
#pragma unroll
    for (int r = 0; r < 4; r++) {
      int row = m0 + wm * 64 + mt * 16 + quad * 4 + r;
      float bias = row < 512 ? bk[row] : (row < 1024 ? bq[row - 512] : bvv[row - 1024]);
#pragma unroll
      for (int nt = 0; nt < 4; nt++) {
        int cn = n0 + wn * 64 + nt * 16 + col;
        KQV[(size_t)row * 65536 + cn] = f2bf(acc[mt][nt][r] + bias);
      }
    }
  }
}

// ---------------- K3: softmax over l (4096, contiguous) on rows 0..511, in place
__global__ void k3_softmax_k(unsigned short* __restrict__ KQV) {
  __shared__ float redm[4];
  __shared__ float reds[4];
  int bid = blockIdx.x;               // 512*16
  int o = bid >> 4, b = bid & 15;
  int t = threadIdx.x;
  unsigned short* rowp = KQV + (size_t)o * 65536 + b * 4096;
  float v[16];
  u16x8 h0 = *(const u16x8*)(rowp + t * 16);
  u16x8 h1 = *(const u16x8*)(rowp + t * 16 + 8);
#pragma unroll
  for (int j = 0; j < 8; j++) { v[j] = bf2f(h0[j]); v[8 + j] = bf2f(h1[j]); }
  float mx = v[0];
#pragma unroll
  for (int j = 1; j < 16; j++) mx = fmaxf(mx, v[j]);
#pragma unroll
  for (int off = 32; off > 0; off >>= 1) mx = fmaxf(mx, __shfl_xor(mx, off));
  if ((t & 63) == 0) redm[t >> 6] = mx;
  __syncthreads();
  mx = fmaxf(fmaxf(redm[0], redm[1]), fmaxf(redm[2], redm[3]));
  float s = 0.f;
#pragma unroll
  for (int j = 0; j < 16; j++) { v[j] = __expf(v[j] - mx); s += v[j]; }
#pragma unroll
  for (int off = 32; off > 0; off >>= 1) s += __shfl_xor(s, off);
  if ((t & 63) == 0) reds[t >> 6] = s;
  __syncthreads();
  s = reds[0] + reds[1] + reds[2] + reds[3];
  float inv = 1.f / s;
  u16x8 o0, o1;
#pragma unroll
  for (int j = 0; j < 8; j++) { o0[j] = f2bf(v[j] * inv); o1[j] = f2bf(v[8 + j] * inv); }
  *(u16x8*)(rowp + t * 16) = o0;
  *(u16x8*)(rowp + t * 16 + 8) = o1;
}

// ---------------- K4: softmax over 64 channels per (b,h,l); writes QT[n][c'] (transposed)
__global__ void __launch_bounds__(256) k4_softmax_q(const unsigned short* __restrict__ KQV,
                                                    unsigned short* __restrict__ QT) {
  int l = blockIdx.x * 256 + threadIdx.x;   // 0..4095
  int h = blockIdx.y, b = blockIdx.z;
  const unsigned short* base = KQV + (size_t)(512 + h * 64) * 65536 + b * 4096 + l;
  float v[64];
#pragma unroll
  for (int kc = 0; kc < 64; kc++) v[kc] = bf2f(base[(size_t)kc * 65536]);
  float mx = v[0];
#pragma unroll
  for (int kc = 1; kc < 64; kc++) mx = fmaxf(mx, v[kc]);
  float s = 0.f;
#pragma unroll
  for (int kc = 0; kc < 64; kc++) { v[kc] = __expf(v[kc] - mx); s += v[kc]; }
  float inv = 1.f / s;
  unsigned short* out = QT + (size_t)(b * 4096 + l) * 512 + h * 64;
#pragma unroll
  for (int j = 0; j < 8; j++) {
    u16x8 o;
#pragma unroll
    for (int e = 0; e < 8; e++) o[e] = f2bf(v[j * 8 + e] * inv);
    *(u16x8*)(out + j * 8) = o;
  }
}

// ---------------- K5: ctx[b,h,kc,vc] += sum_l k'[kc,l]*v[vc,l] (l-split, atomics)
__global__ void __launch_bounds__(256) k5_ctx(const unsigned short* __restrict__ KQV,
                                              float* __restrict__ ctx) {
  __shared__ unsigned short Ks[64 * 32];
  __shared__ unsigned short Vs[64 * 32];
  int t = threadIdx.x;
  int lane = t & 63, w = t >> 6;
  int col = lane & 15, quad = lane >> 4;
  int s = blockIdx.x & 3;
  int h = (blockIdx.x >> 2) & 7;
  int b = blockIdx.x >> 5;
  const unsigned short* Kbase = KQV + (size_t)(h * 64) * 65536 + b * 4096 + s * 1024;
  const unsigned short* Vbase = KQV + (size_t)(1024 + h * 64) * 65536 + b * 4096 + s * 1024;
  f32x4 zero = {0.f, 0.f, 0.f, 0.f};
  f32x4 acc[4];
#pragma unroll
  for (int i = 0; i < 4; i++) acc[i] = zero;
  int row = t >> 2, seg = t & 3;
  for (int kt = 0; kt < 32; kt++) {
    int l0 = kt * 32;
    __syncthreads();
    gl_lds16(Kbase + (size_t)row * 65536 + l0 + seg * 8, (char*)Ks + (t & ~63) * 16);
    gl_lds16(Vbase + (size_t)row * 65536 + l0 + seg * 8, (char*)Vs + (t & ~63) * 16);
    __syncthreads();
    bf16x8 a = *(const bf16x8*)(Ks + (w * 16 + col) * 32 + quad * 8);
#pragma unroll
    for (int nt = 0; nt < 4; nt++) {
      bf16x8 vb = *(const bf16x8*)(Vs + (nt * 16 + col) * 32 + quad * 8);
      acc[nt] = __builtin_amdgcn_mfma_f32_16x16x32_bf16(a, vb, acc[nt], 0, 0, 0);
    }
  }
  float* cbase = ctx + (size_t)(b * 8 + h) * 4096;
#pragma unroll
  for (int nt = 0; nt < 4; nt++)
#pragma unroll
    for (int r = 0; r < 4; r++) {
      int kc = w * 16 + quad * 4 + r;
      int vc = nt * 16 + col;
      atomicAdd(cbase + kc * 64 + vc, acc[nt][r]);
    }
}

// ---------------- K6: M[b][o][h*64+kc] = sum_vc Wr[o][h*64+vc]*ctx[b,h,kc,vc] (bf16)
__global__ void k6_mmat(const float* __restrict__ Wr, const float* __restrict__ ctx,
                        unsigned short* __restrict__ Mb) {
  int idx = blockIdx.x * 256 + threadIdx.x;   // < 16*512*512
  int cp = idx & 511;
  int o = (idx >> 9) & 511;
  int b = idx >> 18;
  int h = cp >> 6, kc = cp & 63;
  const float* wr = Wr + (size_t)o * 512 + h * 64;
  const float* cx = ctx + (size_t)(b * 8 + h) * 4096 + kc * 64;
  float s = 0.f;
#pragma unroll
  for (int vc = 0; vc < 64; vc++) s += wr[vc] * cx[vc];
  Mb[idx] = f2bf(s);
}

// ---------------- K7: out[b][o][l] = Mb[b][o][:] . QT[b*4096+l][:] + br[o], fp32
__global__ void __launch_bounds__(256) k7_out(
    const unsigned short* __restrict__ Mb, const unsigned short* __restrict__ QT,
    const float* __restrict__ br, float* __restrict__ out) {
  __shared__ unsigned short As[128 * 32];
  __shared__ unsigned short Bs[128 * 32];
  const int t = threadIdx.x;
  const int lane = t & 63, w = t >> 6;
  const int wm = w >> 1, wn = w & 1;
  const int m0 = blockIdx.x * 128;
  const int n0 = blockIdx.y * 128;
  const int b = blockIdx.y >> 5;
  const int l0 = (blockIdx.y & 31) * 128;
  const int col = lane & 15, quad = lane >> 4;
  const unsigned short* A = Mb + (size_t)b * 262144;

  f32x4 zero = {0.f, 0.f, 0.f, 0.f};
  f32x4 acc[4][4];
#pragma unroll
  for (int i = 0; i < 4; i++)
#pragma unroll
    for (int j = 0; j < 4; j++) acc[i][j] = zero;

  for (int kt = 0; kt < 16; kt++) {
    const int k0 = kt * 32;
    __syncthreads();
#pragma unroll
    for (int i = 0; i < 2; i++) {
      int lin = i * 256 + t;
      int row = lin >> 2, seg = lin & 3;
      gl_lds16(A + (size_t)(m0 + row) * 512 + k0 + seg * 8,
               (char*)As + (i * 256 + (t & ~63)) * 16);
      gl_lds16(QT + (size_t)(n0 + row) * 512 + k0 + seg * 8,
               (char*)Bs + (i * 256 + (t & ~63)) * 16);
    }
    __syncthreads();
    bf16x8 a[4], bf[4];
#pragma unroll
    for (int mt = 0; mt < 4; mt++)
      a[mt] = *(const bf16x8*)(As + (wm * 64 + mt * 16 + col) * 32 + quad * 8);
#pragma unroll
    for (int nt = 0; nt < 4; nt++)
      bf[nt] = *(const bf16x8*)(Bs + (wn * 64 + nt * 16 + col) * 32 + quad * 8);
#pragma unroll
    for (int mt = 0; mt < 4; mt++)
#pragma unroll
      for (int nt = 0; nt < 4; nt++)
        acc[mt][nt] = __builtin_amdgcn_mfma_f32_16x16x32_bf16(a[mt], bf[nt], acc[mt][nt], 0, 0, 0);
  }
#pragma unroll
  for (int mt = 0; mt < 4; mt++) {
#pragma unroll
    for (int r = 0; r < 4; r++) {
      int row = m0 + wm * 64 + mt * 16 + quad * 4 + r;
      float bias = br[row];
#pragma unroll
      for (int nt = 0; nt < 4; nt++) {
        int l = l0 + wn * 64 + nt * 16 + col;
        out[(size_t)b * 2097152 + (size_t)row * 4096 + l] = acc[mt][nt][r] + bias;
      }
    }
  }
}

extern "C" void kernel_launch(void* const* d_in, const int* in_sizes, int n_in,
                              void* d_out, int out_size, void* d_ws, size_t ws_size,
                              hipStream_t stream) {
  const float* x  = (const float*)d_in[0];
  const float* Wk = (const float*)d_in[1];
  const float* bk = (const float*)d_in[2];
  const float* Wq = (const float*)d_in[3];
  const float* bq = (const float*)d_in[4];
  const float* Wv = (const float*)d_in[5];
  const float* bv = (const float*)d_in[6];
  const float* Wr = (const float*)d_in[7];
  const float* br = (const float*)d_in[8];
  float* out = (float*)d_out;

  char* ws = (char*)d_ws;
  // layout (bytes):
  //   [0, 64M)        XbT bf16 [65536][512]   -- later aliased by QT
  //   [64M, 65.5M)    Wkqv bf16 [1536][512]
  //   [65.5M, 257.5M) KQV bf16 [1536][65536]
  //   [257.5M,259.5M) ctx fp32 [16][8][64][64]
  //   [259.5M,267.5M) Mb bf16 [16][512][512]
  unsigned short* XbT  = (unsigned short*)ws;
  unsigned short* QT   = XbT;  // alias: XbT dead after k2
  unsigned short* Wkqv = (unsigned short*)(ws + 67108864);
  unsigned short* KQV  = (unsigned short*)(ws + 67108864 + 1572864);
  float*          ctx  = (float*)(ws + 67108864 + 1572864 + 201326592);
  unsigned short* Mb   = (unsigned short*)(ws + 67108864 + 1572864 + 201326592 + 2097152);

  k0_pack_w<<<3072, 256, 0, stream>>>(Wk, Wq, Wv, Wkqv);
  k1_transpose_x<<<dim3(64, 8, 16), 256, 0, stream>>>(x, XbT);
  k2_gemm_kqv<<<dim3(12, 512), 256, 0, stream>>>(Wkqv, XbT, bk, bq, bv, KQV);
  k3_softmax_k<<<8192, 256, 0, stream>>>(KQV);
  k4_softmax_q<<<dim3(16, 8, 16), 256, 0, stream>>>(KQV, QT);
  hipMemsetAsync(ctx, 0, 2097152, stream);
  k5_ctx<<<512, 256, 0, stream>>>(KQV, ctx);
  k6_mmat<<<16384, 256, 0, stream>>>(Wr, ctx, Mb);
  k7_out<<<dim3(4, 512), 256, 0, stream>>>(Mb, QT, br, out);
}

// Round 2
// 691.381 us; speedup vs baseline: 1.0082x; 1.0082x over previous
//
#include <hip/hip_runtime.h>
#include <hip/hip_bf16.h>
#include <stdint.h>

// EfficientAttention: B=16, C=512, HW=4096, HEADS=8, hk=hv=64
// N = B*HW = 65536.  Both softmaxes fused into the KQV GEMM epilogue.

typedef __attribute__((ext_vector_type(8))) short bf16x8;
typedef __attribute__((ext_vector_type(8))) unsigned short u16x8;
typedef __attribute__((ext_vector_type(4))) unsigned short u16x4;
typedef __attribute__((ext_vector_type(4))) float f32x4;

__device__ __forceinline__ float bf2f(unsigned short u) {
  union { unsigned int i; float f; } v; v.i = ((unsigned int)u) << 16; return v.f;
}
__device__ __forceinline__ unsigned short f2bf(float f) {
  union { float f; unsigned int i; } v; v.f = f;
  unsigned int u = v.i;
  return (unsigned short)((u + 0x7FFFu + ((u >> 16) & 1u)) >> 16);
}
__device__ __forceinline__ void gl_lds16(const void* g, void* l) {
  __builtin_amdgcn_global_load_lds((const __attribute__((address_space(1))) void*)g,
                                   (__attribute__((address_space(3))) void*)l, 16, 0, 0);
}

// ---------------- K0: pack Wk|Wq|Wv (stacked) to bf16 -----------------------
__global__ void k0_pack_w(const float* __restrict__ Wk, const float* __restrict__ Wq,
                          const float* __restrict__ Wv, unsigned short* __restrict__ Wkqv) {
  int idx = blockIdx.x * 256 + threadIdx.x;   // < 1536*512
  int o = idx >> 9, c = idx & 511;
  float v;
  if (o < 512) v = Wk[o * 512 + c];
  else if (o < 1024) v = Wq[(o - 512) * 512 + c];
  else v = Wv[(o - 1024) * 512 + c];
  Wkqv[idx] = f2bf(v);
}

// ---------------- K1: x[b][c][l] fp32 -> XbT[b*4096+l][c] bf16 (transpose) --
__global__ void k1_transpose_x(const float* __restrict__ x, unsigned short* __restrict__ XbT) {
  __shared__ unsigned short ts[64][68];
  int l0 = blockIdx.x * 64, c0 = blockIdx.y * 64, b = blockIdx.z;
  int t = threadIdx.x;
  const float* xb = x + (size_t)b * (512 * 4096);
#pragma unroll
  for (int i = 0; i < 4; i++) {
    int f = i * 256 + t;
    int cl = f >> 4, l4 = (f & 15) * 4;
    const float4 v = *(const float4*)(xb + (size_t)(c0 + cl) * 4096 + l0 + l4);
    ts[cl][l4]     = f2bf(v.x);
    ts[cl][l4 + 1] = f2bf(v.y);
    ts[cl][l4 + 2] = f2bf(v.z);
    ts[cl][l4 + 3] = f2bf(v.w);
  }
  __syncthreads();
#pragma unroll
  for (int i = 0; i < 4; i++) {
    int wv = i * 256 + t;
    int ll = wv >> 4, c4 = (wv & 15) * 4;
    u16x4 o;
    o.x = ts[c4][ll]; o.y = ts[c4 + 1][ll]; o.z = ts[c4 + 2][ll]; o.w = ts[c4 + 3][ll];
    *(u16x4*)(XbT + (size_t)(b * 4096 + l0 + ll) * 512 + c0 + c4) = o;
  }
}

// ---------------- K2: KQV GEMM + fused softmax epilogues --------------------
// m-blocks 0..3: K rows (raw bf16 out + per-row flash partials over 128 cols)
// m-blocks 4..7: Q rows (in-wave 64-channel softmax, write QT[n][cq] transposed)
// m-blocks 8..11: V rows (plain bf16 out)
__global__ void __launch_bounds__(256) k2_gemm_kqv(
    const unsigned short* __restrict__ Wkqv, const unsigned short* __restrict__ XbT,
    const float* __restrict__ bk, const float* __restrict__ bq, const float* __restrict__ bvv,
    unsigned short* __restrict__ KQV, float2* __restrict__ Kpart) {
  __shared__ unsigned short As[128 * 32];
  __shared__ unsigned short Bs[128 * 32];
  const int t = threadIdx.x;
  const int lane = t & 63, w = t >> 6;
  const int wm = w >> 1, wn = w & 1;
  const int m0 = blockIdx.x * 128, n0 = blockIdx.y * 128;
  const int col = lane & 15, quad = lane >> 4;

  f32x4 zero = {0.f, 0.f, 0.f, 0.f};
  f32x4 acc[4][4];
#pragma unroll
  for (int i = 0; i < 4; i++)
#pragma unroll
    for (int j = 0; j < 4; j++) acc[i][j] = zero;

  for (int kt = 0; kt < 16; kt++) {
    const int k0 = kt * 32;
    __syncthreads();
#pragma unroll
    for (int i = 0; i < 2; i++) {
      int lin = i * 256 + t;
      int row = lin >> 2, seg = lin & 3;
      gl_lds16(Wkqv + (size_t)(m0 + row) * 512 + k0 + seg * 8,
               (char*)As + (i * 256 + (t & ~63)) * 16);
      gl_lds16(XbT + (size_t)(n0 + row) * 512 + k0 + seg * 8,
               (char*)Bs + (i * 256 + (t & ~63)) * 16);
    }
    __syncthreads();
    bf16x8 a[4], bf[4];
#pragma unroll
    for (int mt = 0; mt < 4; mt++)
      a[mt] = *(const bf16x8*)(As + (wm * 64 + mt * 16 + col) * 32 + quad * 8);
#pragma unroll
    for (int nt = 0; nt < 4; nt++)
      bf[nt] = *(const bf16x8*)(Bs + (wn * 64 + nt * 16 + col) * 32 + quad * 8);
#pragma unroll
    for (int mt = 0; mt < 4; mt++)
#pragma unroll
      for (int nt = 0; nt < 4; nt++)
        acc[mt][nt] = __builtin_amdgcn_mfma_f32_16x16x32_bf16(a[mt], bf[nt], acc[mt][nt], 0, 0, 0);
  }

  if (m0 < 512) {
    // ---- K rows: bias + raw write + flash partials (m_p, s_p) over 128 cols
    float lm[4][4];
#pragma unroll
    for (int mt = 0; mt < 4; mt++)
#pragma unroll
      for (int r = 0; r < 4; r++) {
        int row = m0 + wm * 64 + mt * 16 + quad * 4 + r;
        float bias = bk[row];
        float mx = -1e30f;
#pragma unroll
        for (int nt = 0; nt < 4; nt++) {
          acc[mt][nt][r] += bias;
          mx = fmaxf(mx, acc[mt][nt][r]);
          int cn = n0 + wn * 64 + nt * 16 + col;
          KQV[(size_t)row * 65536 + cn] = f2bf(acc[mt][nt][r]);
        }
        lm[mt][r] = mx;
      }
    // reduce max over 16 col-lanes (xor on lane bits 0..3 keeps quad)
#pragma unroll
    for (int mask = 1; mask < 16; mask <<= 1)
#pragma unroll
      for (int mt = 0; mt < 4; mt++)
#pragma unroll
        for (int r = 0; r < 4; r++)
          lm[mt][r] = fmaxf(lm[mt][r], __shfl_xor(lm[mt][r], mask));
    // combine across wn waves via LDS
    float* kred = (float*)As;
    __syncthreads();
    if (col == 0)
#pragma unroll
      for (int mt = 0; mt < 4; mt++)
#pragma unroll
        for (int r = 0; r < 4; r++)
          kred[wn * 128 + wm * 64 + mt * 16 + quad * 4 + r] = lm[mt][r];
    __syncthreads();
#pragma unroll
    for (int mt = 0; mt < 4; mt++)
#pragma unroll
      for (int r = 0; r < 4; r++) {
        int rl = wm * 64 + mt * 16 + quad * 4 + r;
        lm[mt][r] = fmaxf(kred[rl], kred[128 + rl]);
      }
    // partial sums of exp(x - m_p)
    float ls[4][4];
#pragma unroll
    for (int mt = 0; mt < 4; mt++)
#pragma unroll
      for (int r = 0; r < 4; r++) {
        float s = 0.f;
#pragma unroll
        for (int nt = 0; nt < 4; nt++) s += __expf(acc[mt][nt][r] - lm[mt][r]);
        ls[mt][r] = s;
      }
#pragma unroll
    for (int mask = 1; mask < 16; mask <<= 1)
#pragma unroll
      for (int mt = 0; mt < 4; mt++)
#pragma unroll
        for (int r = 0; r < 4; r++)
          ls[mt][r] += __shfl_xor(ls[mt][r], mask);
    __syncthreads();
    if (col == 0)
#pragma unroll
      for (int mt = 0; mt < 4; mt++)
#pragma unroll
        for (int r = 0; r < 4; r++)
          kred[wn * 128 + wm * 64 + mt * 16 + quad * 4 + r] = ls[mt][r];
    __syncthreads();
    if (wn == 0 && col == 0) {
#pragma unroll
      for (int mt = 0; mt < 4; mt++)
#pragma unroll
        for (int r = 0; r < 4; r++) {
          int rl = wm * 64 + mt * 16 + quad * 4 + r;
          float st = kred[rl] + kred[128 + rl];
          Kpart[(size_t)(m0 + rl) * 512 + blockIdx.y] = make_float2(lm[mt][r], st);
        }
    }
  } else if (m0 < 1024) {
    // ---- Q rows: in-wave softmax over the head's 64 channels per column
#pragma unroll
    for (int mt = 0; mt < 4; mt++)
#pragma unroll
      for (int r = 0; r < 4; r++) {
        int row = m0 + wm * 64 + mt * 16 + quad * 4 + r;
        float bias = bq[row - 512];
#pragma unroll
        for (int nt = 0; nt < 4; nt++) acc[mt][nt][r] += bias;
      }
    unsigned short* QT = KQV + (size_t)512 * 65536;
    const int cqb = (m0 - 512) + wm * 64;
#pragma unroll
    for (int nt = 0; nt < 4; nt++) {
      float m = -1e30f;
#pragma unroll
      for (int mt = 0; mt < 4; mt++)
#pragma unroll
        for (int r = 0; r < 4; r++) m = fmaxf(m, acc[mt][nt][r]);
      m = fmaxf(m, __shfl_xor(m, 16));
      m = fmaxf(m, __shfl_xor(m, 32));
      float s = 0.f;
#pragma unroll
      for (int mt = 0; mt < 4; mt++)
#pragma unroll
        for (int r = 0; r < 4; r++) s += __expf(acc[mt][nt][r] - m);
      s += __shfl_xor(s, 16);
      s += __shfl_xor(s, 32);
      float inv = 1.0f / s;
      int n = n0 + wn * 64 + nt * 16 + col;
#pragma unroll
      for (int mt = 0; mt < 4; mt++) {
        u16x4 o;
#pragma unroll
        for (int r = 0; r < 4; r++) o[r] = f2bf(__expf(acc[mt][nt][r] - m) * inv);
        *(u16x4*)(QT + (size_t)n * 512 + cqb + mt * 16 + quad * 4) = o;
      }
    }
  } else {
    // ---- V rows: plain bias + bf16 write
#pragma unroll
    for (int mt = 0; mt < 4; mt++)
#pragma unroll
      for (int r = 0; r < 4; r++) {
        int row = m0 + wm * 64 + mt * 16 + quad * 4 + r;
        float bias = bvv[row - 1024];
#pragma unroll
        for (int nt = 0; nt < 4; nt++) {
          int cn = n0 + wn * 64 + nt * 16 + col;
          KQV[(size_t)row * 65536 + cn] = f2bf(acc[mt][nt][r] + bias);
        }
      }
  }
}

// ---------------- K3c: combine 32 flash partials per (row,b) -> (m, 1/s) ----
__global__ void k3c_combine(const float2* __restrict__ Kpart, float* __restrict__ Ms) {
  int gid = blockIdx.x * 256 + threadIdx.x;  // < 8192 : row = gid>>4, b = gid&15
  int row = gid >> 4, b = gid & 15;
  const float2* kp = Kpart + (size_t)row * 512 + b * 32;
  float m = -1e30f;
#pragma unroll
  for (int j = 0; j < 32; j++) m = fmaxf(m, kp[j].x);
  float s = 0.f;
#pragma unroll
  for (int j = 0; j < 32; j++) s += kp[j].y * __expf(kp[j].x - m);
  Ms[gid * 2] = m;
  Ms[gid * 2 + 1] = 1.0f / s;
}

// ---------------- K5: ctxp[s][b][h][kc][vc] = sum_l exp(k-m)*v (l-split) ----
__global__ void __launch_bounds__(256) k5_ctx(const unsigned short* __restrict__ KQV,
                                              const float* __restrict__ Ms,
                                              float* __restrict__ ctxp) {
  __shared__ unsigned short Ks[64 * 32];
  __shared__ unsigned short Vs[64 * 32];
  int t = threadIdx.x;
  int lane = t & 63, w = t >> 6;
  int col = lane & 15, quad = lane >> 4;
  int s = blockIdx.x & 7;
  int h = (blockIdx.x >> 3) & 7;
  int b = blockIdx.x >> 6;
  int row = t >> 2, seg = t & 3;
  const unsigned short* Kbase = KQV + (size_t)(h * 64) * 65536 + b * 4096 + s * 512;
  const unsigned short* Vbase = KQV + (size_t)(1024 + h * 64) * 65536 + b * 4096 + s * 512;
  float m_row = Ms[((h * 64 + row) * 16 + b) * 2];
  f32x4 zero = {0.f, 0.f, 0.f, 0.f};
  f32x4 acc[4];
#pragma unroll
  for (int i = 0; i < 4; i++) acc[i] = zero;
  for (int kt = 0; kt < 16; kt++) {
    int l0 = kt * 32;
    u16x8 kv = *(const u16x8*)(Kbase + (size_t)row * 65536 + l0 + seg * 8);
    u16x8 ke;
#pragma unroll
    for (int j = 0; j < 8; j++) ke[j] = f2bf(__expf(bf2f(kv[j]) - m_row));
    __syncthreads();
    *(u16x8*)(Ks + t * 8) = ke;
    gl_lds16(Vbase + (size_t)row * 65536 + l0 + seg * 8, (char*)Vs + (t & ~63) * 16);
    __syncthreads();
    bf16x8 a = *(const bf16x8*)(Ks + (w * 16 + col) * 32 + quad * 8);
#pragma unroll
    for (int nt = 0; nt < 4; nt++) {
      bf16x8 vb = *(const bf16x8*)(Vs + (nt * 16 + col) * 32 + quad * 8);
      acc[nt] = __builtin_amdgcn_mfma_f32_16x16x32_bf16(a, vb, acc[nt], 0, 0, 0);
    }
  }
  float* cb = ctxp + (((size_t)s * 16 + b) * 8 + h) * 4096;
#pragma unroll
  for (int nt = 0; nt < 4; nt++)
#pragma unroll
    for (int r = 0; r < 4; r++)
      cb[(w * 16 + quad * 4 + r) * 64 + nt * 16 + col] = acc[nt][r];
}

// ---------------- K6a: reduce 8 l-split slices -> ctx -----------------------
__global__ void k6a_reduce(const float* __restrict__ ctxp, float* __restrict__ ctx) {
  int idx = blockIdx.x * 256 + threadIdx.x;  // < 524288
  float s = 0.f;
#pragma unroll
  for (int sl = 0; sl < 8; sl++) s += ctxp[(size_t)sl * 524288 + idx];
  ctx[idx] = s;
}

// ---------------- K6b: M[b][o][cq] = inv_s * sum_vc Wr[o][h*64+vc]*ctx ------
__global__ void k6b_mmat(const float* __restrict__ Wr, const float* __restrict__ ctx,
                         const float* __restrict__ Ms, unsigned short* __restrict__ Mb) {
  int idx = blockIdx.x * 256 + threadIdx.x;   // < 16*512*512
  int cp = idx & 511;
  int o = (idx >> 9) & 511;
  int b = idx >> 18;
  int h = cp >> 6, kc = cp & 63;
  const float* wr = Wr + (size_t)o * 512 + h * 64;
  const float* cx = ctx + (size_t)(b * 8 + h) * 4096 + kc * 64;
  float s = 0.f;
#pragma unroll
  for (int vc = 0; vc < 64; vc += 4) {
    float4 a = *(const float4*)(wr + vc);
    float4 c = *(const float4*)(cx + vc);
    s += a.x * c.x + a.y * c.y + a.z * c.z + a.w * c.w;
  }
  float inv = Ms[(cp * 16 + b) * 2 + 1];
  Mb[idx] = f2bf(s * inv);
}

// ---------------- K7: out[b][o][l] = Mb[b][o][:] . QT[b*4096+l][:] + br[o] --
__global__ void __launch_bounds__(256) k7_out(
    const unsigned short* __restrict__ Mb, const unsigned short* __restrict__ QT,
    const float* __restrict__ br, float* __restrict__ out) {
  __shared__ unsigned short As[128 * 32];
  __shared__ unsigned short Bs[128 * 32];
  const int t = threadIdx.x;
  const int lane = t & 63, w = t >> 6;
  const int wm = w >> 1, wn = w & 1;
  const int m0 = blockIdx.x * 128;
  const int n0 = blockIdx.y * 128;
  const int b = blockIdx.y >> 5;
  const int l0 = (blockIdx.y & 31) * 128;
  const int col = lane & 15, quad = lane >> 4;
  const unsigned short* A = Mb + (size_t)b * 262144;

  f32x4 zero = {0.f, 0.f, 0.f, 0.f};
  f32x4 acc[4][4];
#pragma unroll
  for (int i = 0; i < 4; i++)
#pragma unroll
    for (int j = 0; j < 4; j++) acc[i][j] = zero;

  for (int kt = 0; kt < 16; kt++) {
    const int k0 = kt * 32;
    __syncthreads();
#pragma unroll
    for (int i = 0; i < 2; i++) {
      int lin = i * 256 + t;
      int row = lin >> 2, seg = lin & 3;
      gl_lds16(A + (size_t)(m0 + row) * 512 + k0 + seg * 8,
               (char*)As + (i * 256 + (t & ~63)) * 16);
      gl_lds16(QT + (size_t)(n0 + row) * 512 + k0 + seg * 8,
               (char*)Bs + (i * 256 + (t & ~63)) * 16);
    }
    __syncthreads();
    bf16x8 a[4], bf[4];
#pragma unroll
    for (int mt = 0; mt < 4; mt++)
      a[mt] = *(const bf16x8*)(As + (wm * 64 + mt * 16 + col) * 32 + quad * 8);
#pragma unroll
    for (int nt = 0; nt < 4; nt++)
      bf[nt] = *(const bf16x8*)(Bs + (wn * 64 + nt * 16 + col) * 32 + quad * 8);
#pragma unroll
    for (int mt = 0; mt < 4; mt++)
#pragma unroll
      for (int nt = 0; nt < 4; nt++)
        acc[mt][nt] = __builtin_amdgcn_mfma_f32_16x16x32_bf16(a[mt], bf[nt], acc[mt][nt], 0, 0, 0);
  }
#pragma unroll
  for (int mt = 0; mt < 4; mt++) {
#pragma unroll
    for (int r = 0; r < 4; r++) {
      int row = m0 + wm * 64 + mt * 16 + quad * 4 + r;
      float bias = br[row];
#pragma unroll
      for (int nt = 0; nt < 4; nt++) {
        int l = l0 + wn * 64 + nt * 16 + col;
        out[(size_t)b * 2097152 + (size_t)row * 4096 + l] = acc[mt][nt][r] + bias;
      }
    }
  }
}

extern "C" void kernel_launch(void* const* d_in, const int* in_sizes, int n_in,
                              void* d_out, int out_size, void* d_ws, size_t ws_size,
                              hipStream_t stream) {
  const float* x  = (const float*)d_in[0];
  const float* Wk = (const float*)d_in[1];
  const float* bk = (const float*)d_in[2];
  const float* Wq = (const float*)d_in[3];
  const float* bq = (const float*)d_in[4];
  const float* Wv = (const float*)d_in[5];
  const float* bv = (const float*)d_in[6];
  const float* Wr = (const float*)d_in[7];
  const float* br = (const float*)d_in[8];
  float* out = (float*)d_out;

  char* ws = (char*)d_ws;
  // layout (bytes):
  //   [0, 64Mi)          XbT bf16 [65536][512]   (dead after k2; reused below)
  //   [64Mi, 65.5Mi)     Wkqv bf16 [1536][512]
  //   [65.5Mi, 257.5Mi)  KQV bf16 [1536][65536]; rows 512..1023 = QT[n][512]
  //   [257.5Mi, 259.5Mi) Kpart float2 [512][512]
  //   after k2 (inside old XbT region):
  //   [0, 64Ki)          Ms float2 [512][16]  (m, 1/s)
  //   [1Mi, 17Mi)        ctxp fp32 [8][16][8][64][64]
  //   [17Mi, 19Mi)       ctx  fp32 [16][8][64][64]
  //   [19Mi, 27Mi)       Mb bf16 [16][512][512]
  const size_t MiB = 1024 * 1024;
  unsigned short* XbT  = (unsigned short*)ws;
  unsigned short* Wkqv = (unsigned short*)(ws + 64 * MiB);
  unsigned short* KQV  = (unsigned short*)(ws + 64 * MiB + 1536 * 1024);
  unsigned short* QT   = KQV + (size_t)512 * 65536;
  float2*         Kpart = (float2*)(ws + 64 * MiB + 1536 * 1024 + 192 * MiB);
  float*          Ms   = (float*)ws;
  float*          ctxp = (float*)(ws + 1 * MiB);
  float*          ctx  = (float*)(ws + 17 * MiB);
  unsigned short* Mb   = (unsigned short*)(ws + 19 * MiB);

  k0_pack_w<<<3072, 256, 0, stream>>>(Wk, Wq, Wv, Wkqv);
  k1_transpose_x<<<dim3(64, 8, 16), 256, 0, stream>>>(x, XbT);
  k2_gemm_kqv<<<dim3(12, 512), 256, 0, stream>>>(Wkqv, XbT, bk, bq, bv, KQV, Kpart);
  k3c_combine<<<32, 256, 0, stream>>>(Kpart, Ms);
  k5_ctx<<<1024, 256, 0, stream>>>(KQV, Ms, ctxp);
  k6a_reduce<<<2048, 256, 0, stream>>>(ctxp, ctx);
  k6b_mmat<<<16384, 256, 0, stream>>>(Wr, ctx, Ms, Mb);
  k7_out<<<dim3(4, 512), 256, 0, stream>>>(Mb, QT, br, out);
}

// Round 3
// 542.699 us; speedup vs baseline: 1.2844x; 1.2740x over previous
//
#include <hip/hip_runtime.h>
#include <hip/hip_bf16.h>
#include <stdint.h>

// EfficientAttention: B=16, C=512, HW=4096, HEADS=8, hk=hv=64
// N = B*HW = 65536.

typedef __attribute__((ext_vector_type(8))) short bf16x8;
typedef __attribute__((ext_vector_type(8))) unsigned short u16x8;
typedef __attribute__((ext_vector_type(4))) unsigned short u16x4;
typedef __attribute__((ext_vector_type(4))) float f32x4;

__device__ __forceinline__ float bf2f(unsigned short u) {
  union { unsigned int i; float f; } v; v.i = ((unsigned int)u) << 16; return v.f;
}
__device__ __forceinline__ unsigned short f2bf(float f) {
  union { float f; unsigned int i; } v; v.f = f;
  unsigned int u = v.i;
  return (unsigned short)((u + 0x7FFFu + ((u >> 16) & 1u)) >> 16);
}
__device__ __forceinline__ void gl_lds16(const void* g, void* l) {
  __builtin_amdgcn_global_load_lds((const __attribute__((address_space(1))) void*)g,
                                   (__attribute__((address_space(3))) void*)l, 16, 0, 0);
}

// ---------------- K0: pack Wk|Wq|Wv (stacked) to bf16 -----------------------
__global__ void k0_pack_w(const float* __restrict__ Wk, const float* __restrict__ Wq,
                          const float* __restrict__ Wv, unsigned short* __restrict__ Wkqv) {
  int idx = blockIdx.x * 256 + threadIdx.x;   // < 1536*512
  int o = idx >> 9, c = idx & 511;
  float v;
  if (o < 512) v = Wk[o * 512 + c];
  else if (o < 1024) v = Wq[(o - 512) * 512 + c];
  else v = Wv[(o - 1024) * 512 + c];
  Wkqv[idx] = f2bf(v);
}

// ---------------- K1: x[b][c][l] fp32 -> XbT[b*4096+l][c] bf16 (transpose) --
__global__ void k1_transpose_x(const float* __restrict__ x, unsigned short* __restrict__ XbT) {
  __shared__ unsigned short ts[64][68];
  int l0 = blockIdx.x * 64, c0 = blockIdx.y * 64, b = blockIdx.z;
  int t = threadIdx.x;
  const float* xb = x + (size_t)b * (512 * 4096);
#pragma unroll
  for (int i = 0; i < 4; i++) {
    int f = i * 256 + t;
    int cl = f >> 4, l4 = (f & 15) * 4;
    const float4 v = *(const float4*)(xb + (size_t)(c0 + cl) * 4096 + l0 + l4);
    ts[cl][l4]     = f2bf(v.x);
    ts[cl][l4 + 1] = f2bf(v.y);
    ts[cl][l4 + 2] = f2bf(v.z);
    ts[cl][l4 + 3] = f2bf(v.w);
  }
  __syncthreads();
#pragma unroll
  for (int i = 0; i < 4; i++) {
    int wv = i * 256 + t;
    int ll = wv >> 4, c4 = (wv & 15) * 4;
    u16x4 o;
    o.x = ts[c4][ll]; o.y = ts[c4 + 1][ll]; o.z = ts[c4 + 2][ll]; o.w = ts[c4 + 3][ll];
    *(u16x4*)(XbT + (size_t)(b * 4096 + l0 + ll) * 512 + c0 + c4) = o;
  }
}

// ---------------- K2: KQV GEMM; Q-softmax fused; XCD-swizzled grid ----------
// m-blocks 0..3: K rows (bias + raw bf16)
// m-blocks 4..7: Q rows (in-wave 64-channel softmax, write QT[n][cq] transposed)
// m-blocks 8..11: V rows (bias + raw bf16)
__global__ void __launch_bounds__(256) k2_gemm_kqv(
    const unsigned short* __restrict__ Wkqv, const unsigned short* __restrict__ XbT,
    const float* __restrict__ bk, const float* __restrict__ bq, const float* __restrict__ bvv,
    unsigned short* __restrict__ KQV) {
  __shared__ unsigned short As[128 * 32];
  __shared__ unsigned short Bs[128 * 32];
  const int t = threadIdx.x;
  const int lane = t & 63, w = t >> 6;
  const int wm = w >> 1, wn = w & 1;
  // XCD swizzle: all 12 m-tiles of one n-tile go to the same XCD (id = g&7),
  // dispatched back-to-back -> B-tile lives in that XCD's L2.
  const int g = blockIdx.x;           // 0..6143
  const int xcd = g & 7, j = g >> 3;  // j: 0..767
  const int m0 = (j % 12) * 128;
  const int n0 = ((j / 12) * 8 + xcd) * 128;
  const int col = lane & 15, quad = lane >> 4;

  f32x4 zero = {0.f, 0.f, 0.f, 0.f};
  f32x4 acc[4][4];
#pragma unroll
  for (int i = 0; i < 4; i++)
#pragma unroll
    for (int jj = 0; jj < 4; jj++) acc[i][jj] = zero;

  for (int kt = 0; kt < 16; kt++) {
    const int k0 = kt * 32;
    __syncthreads();
#pragma unroll
    for (int i = 0; i < 2; i++) {
      int lin = i * 256 + t;
      int row = lin >> 2, seg = lin & 3;
      gl_lds16(Wkqv + (size_t)(m0 + row) * 512 + k0 + seg * 8,
               (char*)As + (i * 256 + (t & ~63)) * 16);
      gl_lds16(XbT + (size_t)(n0 + row) * 512 + k0 + seg * 8,
               (char*)Bs + (i * 256 + (t & ~63)) * 16);
    }
    __syncthreads();
    bf16x8 a[4], bf[4];
#pragma unroll
    for (int mt = 0; mt < 4; mt++)
      a[mt] = *(const bf16x8*)(As + (wm * 64 + mt * 16 + col) * 32 + quad * 8);
#pragma unroll
    for (int nt = 0; nt < 4; nt++)
      bf[nt] = *(const bf16x8*)(Bs + (wn * 64 + nt * 16 + col) * 32 + quad * 8);
#pragma unroll
    for (int mt = 0; mt < 4; mt++)
#pragma unroll
      for (int nt = 0; nt < 4; nt++)
        acc[mt][nt] = __builtin_amdgcn_mfma_f32_16x16x32_bf16(a[mt], bf[nt], acc[mt][nt], 0, 0, 0);
  }

  if (m0 < 512 || m0 >= 1024) {
    // ---- K / V rows: bias + raw bf16 write
#pragma unroll
    for (int mt = 0; mt < 4; mt++)
#pragma unroll
      for (int r = 0; r < 4; r++) {
        int row = m0 + wm * 64 + mt * 16 + quad * 4 + r;
        float bias = (m0 < 512) ? bk[row] : bvv[row - 1024];
#pragma unroll
        for (int nt = 0; nt < 4; nt++) {
          int cn = n0 + wn * 64 + nt * 16 + col;
          KQV[(size_t)row * 65536 + cn] = f2bf(acc[mt][nt][r] + bias);
        }
      }
  } else {
    // ---- Q rows: in-wave softmax over the head's 64 channels per column
#pragma unroll
    for (int mt = 0; mt < 4; mt++)
#pragma unroll
      for (int r = 0; r < 4; r++) {
        int row = m0 + wm * 64 + mt * 16 + quad * 4 + r;
        float bias = bq[row - 512];
#pragma unroll
        for (int nt = 0; nt < 4; nt++) acc[mt][nt][r] += bias;
      }
    unsigned short* QT = KQV + (size_t)512 * 65536;
    const int cqb = (m0 - 512) + wm * 64;
#pragma unroll
    for (int nt = 0; nt < 4; nt++) {
      float m = -1e30f;
#pragma unroll
      for (int mt = 0; mt < 4; mt++)
#pragma unroll
        for (int r = 0; r < 4; r++) m = fmaxf(m, acc[mt][nt][r]);
      m = fmaxf(m, __shfl_xor(m, 16));
      m = fmaxf(m, __shfl_xor(m, 32));
      float s = 0.f;
#pragma unroll
      for (int mt = 0; mt < 4; mt++)
#pragma unroll
        for (int r = 0; r < 4; r++) s += __expf(acc[mt][nt][r] - m);
      s += __shfl_xor(s, 16);
      s += __shfl_xor(s, 32);
      float inv = 1.0f / s;
      int n = n0 + wn * 64 + nt * 16 + col;
#pragma unroll
      for (int mt = 0; mt < 4; mt++) {
        u16x4 o;
#pragma unroll
        for (int r = 0; r < 4; r++) o[r] = f2bf(__expf(acc[mt][nt][r] - m) * inv);
        *(u16x4*)(QT + (size_t)n * 512 + cqb + mt * 16 + quad * 4) = o;
      }
    }
  }
}

// ---------------- K5: online-flash ctx partials per l-split -----------------
// ctxp[s][b][h][kc][vc] = sum_{l in split} exp(k - m_s) * v ; Msp = (m_s, s_s)
__global__ void __launch_bounds__(256) k5_ctx(const unsigned short* __restrict__ KQV,
                                              float* __restrict__ ctxp,
                                              float2* __restrict__ Msp) {
  __shared__ unsigned short Ks[64 * 32];
  __shared__ unsigned short Vs[64 * 32];
  __shared__ float red[64 * 4];
  int t = threadIdx.x;
  int lane = t & 63, w = t >> 6;
  int col = lane & 15, quad = lane >> 4;
  int s = blockIdx.x & 7;
  int h = (blockIdx.x >> 3) & 7;
  int b = blockIdx.x >> 6;
  int row = t >> 2, seg = t & 3;
  const unsigned short* Kbase = KQV + (size_t)(h * 64) * 65536 + b * 4096 + s * 512;
  const unsigned short* Vbase = KQV + (size_t)(1024 + h * 64) * 65536 + b * 4096 + s * 512;
  const unsigned short* krow = Kbase + (size_t)row * 65536;

  // pass A: per-row max over this split's 512 l's (each thread: 128 of them)
  float mx = -1e30f;
#pragma unroll
  for (int kt = 0; kt < 16; kt++) {
    u16x8 kv = *(const u16x8*)(krow + kt * 32 + seg * 8);
#pragma unroll
    for (int jj = 0; jj < 8; jj++) mx = fmaxf(mx, bf2f(kv[jj]));
  }
  red[row * 4 + seg] = mx;
  __syncthreads();
  float m_row = fmaxf(fmaxf(red[row * 4], red[row * 4 + 1]),
                      fmaxf(red[row * 4 + 2], red[row * 4 + 3]));

  // pass B: exp (L2-hot re-read) + MFMA, accumulate per-thread sum of exps
  float sexp = 0.f;
  f32x4 zero = {0.f, 0.f, 0.f, 0.f};
  f32x4 acc[4];
#pragma unroll
  for (int i = 0; i < 4; i++) acc[i] = zero;
  for (int kt = 0; kt < 16; kt++) {
    int l0 = kt * 32;
    u16x8 kv = *(const u16x8*)(krow + l0 + seg * 8);
    u16x8 ke;
#pragma unroll
    for (int jj = 0; jj < 8; jj++) {
      float e = __expf(bf2f(kv[jj]) - m_row);
      sexp += e;
      ke[jj] = f2bf(e);
    }
    __syncthreads();
    *(u16x8*)(Ks + t * 8) = ke;
    gl_lds16(Vbase + (size_t)row * 65536 + l0 + seg * 8, (char*)Vs + (t & ~63) * 16);
    __syncthreads();
    bf16x8 a = *(const bf16x8*)(Ks + (w * 16 + col) * 32 + quad * 8);
#pragma unroll
    for (int nt = 0; nt < 4; nt++) {
      bf16x8 vb = *(const bf16x8*)(Vs + (nt * 16 + col) * 32 + quad * 8);
      acc[nt] = __builtin_amdgcn_mfma_f32_16x16x32_bf16(a, vb, acc[nt], 0, 0, 0);
    }
  }
  red[row * 4 + seg] = sexp;
  float* cb = ctxp + (((size_t)s * 16 + b) * 8 + h) * 4096;
#pragma unroll
  for (int nt = 0; nt < 4; nt++)
#pragma unroll
    for (int r = 0; r < 4; r++)
      cb[(w * 16 + quad * 4 + r) * 64 + nt * 16 + col] = acc[nt][r];
  __syncthreads();
  if (seg == 0) {
    float s_row = red[row * 4] + red[row * 4 + 1] + red[row * 4 + 2] + red[row * 4 + 3];
    Msp[((size_t)(b * 8 + h) * 64 + row) * 8 + s] = make_float2(m_row, s_row);
  }
}

// ---------------- K6: fused rescale-combine + Wr fold -> Mb (bf16) ----------
// Mb[b][o][h*64+kc] = (1/s_g) * sum_vc Wr[o][h*64+vc] * sum_s exp(m_s-m_g)*ctxp
__global__ void __launch_bounds__(256) k6_fold(const float* __restrict__ Wr,
                                               const float* __restrict__ ctxp,
                                               const float2* __restrict__ Msp,
                                               unsigned short* __restrict__ Mb) {
  __shared__ float gf[8][64];     // inv-scaled rescale factors per (s, kc)
  __shared__ float ctxs[64][64];  // rescaled ctx tile, 16 KB
  int oc = blockIdx.x, h = blockIdx.y, b = blockIdx.z;
  int t = threadIdx.x;
  if (t < 64) {
    int kc = t;
    const float2* mp = Msp + ((size_t)(b * 8 + h) * 64 + kc) * 8;
    float2 v[8];
    float m = -1e30f;
#pragma unroll
    for (int s = 0; s < 8; s++) { v[s] = mp[s]; m = fmaxf(m, v[s].x); }
    float f[8], ssum = 0.f;
#pragma unroll
    for (int s = 0; s < 8; s++) { f[s] = __expf(v[s].x - m); ssum += v[s].y * f[s]; }
    float inv = 1.0f / ssum;
#pragma unroll
    for (int s = 0; s < 8; s++) gf[s][kc] = f[s] * inv;
  }
  __syncthreads();
#pragma unroll
  for (int i = 0; i < 16; i++) {
    int p = i * 256 + t;
    int kc = p >> 6;
    float a = 0.f;
#pragma unroll
    for (int s = 0; s < 8; s++)
      a += ctxp[(((size_t)s * 16 + b) * 8 + h) * 4096 + p] * gf[s][kc];
    ((float*)ctxs)[p] = a;
  }
  __syncthreads();
  // mini-GEMM: 128 o-rows x 32 kc per thread-half, K=64 from LDS
  int o = oc * 128 + (t >> 1);
  int kh = (t & 1) * 32;
  const float* wrp = Wr + (size_t)o * 512 + h * 64;
  float acc2[32];
#pragma unroll
  for (int kc = 0; kc < 32; kc++) acc2[kc] = 0.f;
#pragma unroll
  for (int v4 = 0; v4 < 16; v4++) {
    float4 wv = *(const float4*)(wrp + v4 * 4);
#pragma unroll
    for (int kc = 0; kc < 32; kc++) {
      const float4 c4 = *(const float4*)(&ctxs[kh + kc][v4 * 4]);
      acc2[kc] += wv.x * c4.x + wv.y * c4.y + wv.z * c4.z + wv.w * c4.w;
    }
  }
  unsigned short* mp = Mb + (size_t)b * 262144 + (size_t)o * 512 + h * 64 + kh;
#pragma unroll
  for (int jj = 0; jj < 4; jj++) {
    u16x8 ov;
#pragma unroll
    for (int e = 0; e < 8; e++) ov[e] = f2bf(acc2[jj * 8 + e]);
    *(u16x8*)(mp + jj * 8) = ov;
  }
}

// ---------------- K7: out[b][o][l] = Mb[b][o][:] . QT[b*4096+l][:] + br[o] --
__global__ void __launch_bounds__(256) k7_out(
    const unsigned short* __restrict__ Mb, const unsigned short* __restrict__ QT,
    const float* __restrict__ br, float* __restrict__ out) {
  __shared__ unsigned short As[128 * 32];
  __shared__ unsigned short Bs[128 * 32];
  const int t = threadIdx.x;
  const int lane = t & 63, w = t >> 6;
  const int wm = w >> 1, wn = w & 1;
  // XCD swizzle: the 4 m-tiles of one n-tile co-locate on one XCD.
  const int g = blockIdx.x;           // 0..2047
  const int xcd = g & 7, j = g >> 3;  // j: 0..255
  const int m0 = (j & 3) * 128;
  const int nlin = (j >> 2) * 8 + xcd;  // 0..511
  const int b = nlin >> 5;
  const int l0 = (nlin & 31) * 128;
  const int n0 = nlin * 128;
  const int col = lane & 15, quad = lane >> 4;
  const unsigned short* A = Mb + (size_t)b * 262144;

  f32x4 zero = {0.f, 0.f, 0.f, 0.f};
  f32x4 acc[4][4];
#pragma unroll
  for (int i = 0; i < 4; i++)
#pragma unroll
    for (int jj = 0; jj < 4; jj++) acc[i][jj] = zero;

  for (int kt = 0; kt < 16; kt++) {
    const int k0 = kt * 32;
    __syncthreads();
#pragma unroll
    for (int i = 0; i < 2; i++) {
      int lin = i * 256 + t;
      int row = lin >> 2, seg = lin & 3;
      gl_lds16(A + (size_t)(m0 + row) * 512 + k0 + seg * 8,
               (char*)As + (i * 256 + (t & ~63)) * 16);
      gl_lds16(QT + (size_t)(n0 + row) * 512 + k0 + seg * 8,
               (char*)Bs + (i * 256 + (t & ~63)) * 16);
    }
    __syncthreads();
    bf16x8 a[4], bf[4];
#pragma unroll
    for (int mt = 0; mt < 4; mt++)
      a[mt] = *(const bf16x8*)(As + (wm * 64 + mt * 16 + col) * 32 + quad * 8);
#pragma unroll
    for (int nt = 0; nt < 4; nt++)
      bf[nt] = *(const bf16x8*)(Bs + (wn * 64 + nt * 16 + col) * 32 + quad * 8);
#pragma unroll
    for (int mt = 0; mt < 4; mt++)
#pragma unroll
      for (int nt = 0; nt < 4; nt++)
        acc[mt][nt] = __builtin_amdgcn_mfma_f32_16x16x32_bf16(a[mt], bf[nt], acc[mt][nt], 0, 0, 0);
  }
#pragma unroll
  for (int mt = 0; mt < 4; mt++) {
#pragma unroll
    for (int r = 0; r < 4; r++) {
      int row = m0 + wm * 64 + mt * 16 + quad * 4 + r;
      float bias = br[row];
#pragma unroll
      for (int nt = 0; nt < 4; nt++) {
        int l = l0 + wn * 64 + nt * 16 + col;
        out[(size_t)b * 2097152 + (size_t)row * 4096 + l] = acc[mt][nt][r] + bias;
      }
    }
  }
}

extern "C" void kernel_launch(void* const* d_in, const int* in_sizes, int n_in,
                              void* d_out, int out_size, void* d_ws, size_t ws_size,
                              hipStream_t stream) {
  const float* x  = (const float*)d_in[0];
  const float* Wk = (const float*)d_in[1];
  const float* bk = (const float*)d_in[2];
  const float* Wq = (const float*)d_in[3];
  const float* bq = (const float*)d_in[4];
  const float* Wv = (const float*)d_in[5];
  const float* bv = (const float*)d_in[6];
  const float* Wr = (const float*)d_in[7];
  const float* br = (const float*)d_in[8];
  float* out = (float*)d_out;

  char* ws = (char*)d_ws;
  // layout (bytes):
  //   [0, 64Mi)          XbT bf16 [65536][512]   (dead after k2; reused below)
  //   [64Mi, 65.5Mi)     Wkqv bf16 [1536][512]
  //   [65.5Mi, 257.5Mi)  KQV bf16 [1536][65536]; rows 512..1023 = QT[n][512]
  //   after k2 (inside old XbT region):
  //   [0, 0.5Mi)         Msp float2 [16][8][64][8]  (m_s, s_s)
  //   [1Mi, 17Mi)        ctxp fp32 [8][16][8][64][64]
  //   [20Mi, 28Mi)       Mb bf16 [16][512][512]
  const size_t MiB = 1024 * 1024;
  unsigned short* XbT  = (unsigned short*)ws;
  unsigned short* Wkqv = (unsigned short*)(ws + 64 * MiB);
  unsigned short* KQV  = (unsigned short*)(ws + 64 * MiB + 1536 * 1024);
  unsigned short* QT   = KQV + (size_t)512 * 65536;
  float2*         Msp  = (float2*)ws;
  float*          ctxp = (float*)(ws + 1 * MiB);
  unsigned short* Mb   = (unsigned short*)(ws + 20 * MiB);

  k0_pack_w<<<3072, 256, 0, stream>>>(Wk, Wq, Wv, Wkqv);
  k1_transpose_x<<<dim3(64, 8, 16), 256, 0, stream>>>(x, XbT);
  k2_gemm_kqv<<<6144, 256, 0, stream>>>(Wkqv, XbT, bk, bq, bv, KQV);
  k5_ctx<<<1024, 256, 0, stream>>>(KQV, ctxp, Msp);
  k6_fold<<<dim3(4, 8, 16), 256, 0, stream>>>(Wr, ctxp, Msp, Mb);
  k7_out<<<2048, 256, 0, stream>>>(Mb, QT, br, out);
}